// Round 1
// baseline (210.183 us; speedup 1.0000x reference)
//
#include <hip/hip_runtime.h>
#include <math.h>

#define BATCH 32
#define NA 8400
#define NMAX 32
#define NC 80
#define TOPK 13
#define THREADS 256
#define NPT 33  // ceil(8400/256)

// flat output offsets (elements)
#define OFF_BOX 268800
#define OFF_SCR 1344000
#define OFF_FG  22848000
#define OFF_TGT 23116800

__device__ __forceinline__ float ciou_f(float gx1, float gy1, float gx2, float gy2,
                                        float px1, float py1, float px2, float py2) {
    const float eps = 1e-7f;
    float iw = fmaxf(fminf(gx2, px2) - fmaxf(gx1, px1), 0.0f);
    float ih = fmaxf(fminf(gy2, py2) - fmaxf(gy1, py1), 0.0f);
    float inter = iw * ih;
    float w1 = gx2 - gx1, h1 = gy2 - gy1 + eps;
    float w2 = px2 - px1, h2 = py2 - py1 + eps;
    float uni = w1 * h1 + w2 * h2 - inter + eps;
    float iou = inter / uni;
    float cw = fmaxf(gx2, px2) - fminf(gx1, px1);
    float ch = fmaxf(gy2, py2) - fminf(gy1, py1);
    float c2 = cw * cw + ch * ch + eps;
    float dx = px1 + px2 - gx1 - gx2;
    float dy = py1 + py2 - gy1 - gy2;
    float rho2 = (dx * dx + dy * dy) / 4.0f;
    float dd = atanf(w2 / h2) - atanf(w1 / h1);
    float v = (float)(4.0 / (M_PI * M_PI)) * dd * dd;
    float alpha = v / (v - iou + (1.0f + eps));
    return iou - (rho2 / c2 + v * alpha);
}

// One block per (b, gt). Computes align metric over all anchors, selects top-13
// (tie-break: lower anchor index, matching lax.top_k), ORs bit gt into mask[b][a].
__global__ __launch_bounds__(THREADS) void topk_kernel(
    const float* __restrict__ pd_scores, const float* __restrict__ pd_bboxes,
    const int* __restrict__ gt_labels, const float* __restrict__ gt_bboxes,
    unsigned int* __restrict__ mask) {
    const int tid = threadIdx.x;
    const int bid = blockIdx.x;
    const int b  = bid >> 5;
    const int gi = bid & 31;

    const float4 g = ((const float4*)gt_bboxes)[b * NMAX + gi];
    const int lbl = gt_labels[b * NMAX + gi];

    // per-thread metric slice, statically indexed only (stays in VGPRs)
    float m[NPT];
#pragma unroll
    for (int j = 0; j < NPT; j++) {
        int a = j * THREADS + tid;
        float met = -INFINITY;
        if (a < NA) {
            float4 p = ((const float4*)pd_bboxes)[(size_t)b * NA + a];
            float ov = ciou_f(g.x, g.y, g.z, g.w, p.x, p.y, p.z, p.w);
            float sc = pd_scores[((size_t)b * NA + a) * NC + lbl];
            float ov2 = ov * ov;
            met = sc * (ov2 * ov2 * ov2);   // score^1 * ciou^6
        }
        m[j] = met;
    }

    __shared__ float sv[4];
    __shared__ int   sa[4];
    __shared__ float swv;
    __shared__ int   swa;

    // last selected winner in (value desc, index asc) total order
    float wv = INFINITY;
    int   wa = -1;

    for (int k = 0; k < TOPK; k++) {
        // per-thread best strictly below last winner (no register-array mutation)
        float bv = -INFINITY;
        int   ba = 0x7FFFFFFF;
#pragma unroll
        for (int j = 0; j < NPT; j++) {
            int a = j * THREADS + tid;
            float v = m[j];
            bool below_win = (v < wv) || (v == wv && a > wa);
            bool beats     = (v > bv) || (v == bv && a < ba);
            if (below_win && beats) { bv = v; ba = a; }
        }
        // wave (64-lane) reduce
        float v = bv; int a = ba;
        for (int off = 32; off > 0; off >>= 1) {
            float ov = __shfl_down(v, off);
            int   oa = __shfl_down(a, off);
            if (ov > v || (ov == v && oa < a)) { v = ov; a = oa; }
        }
        if ((tid & 63) == 0) { sv[tid >> 6] = v; sa[tid >> 6] = a; }
        __syncthreads();
        if (tid == 0) {
            float fv = sv[0]; int fa = sa[0];
            for (int w = 1; w < 4; w++)
                if (sv[w] > fv || (sv[w] == fv && sa[w] < fa)) { fv = sv[w]; fa = sa[w]; }
            swv = fv; swa = fa;
            atomicOr(&mask[(size_t)b * NA + fa], 1u << gi);
        }
        __syncthreads();
        wv = swv; wa = swa;
    }
}

// One thread per (b, anchor): resolve assignment + write all five outputs.
__global__ __launch_bounds__(THREADS) void assign_kernel(
    const float* __restrict__ pd_bboxes, const int* __restrict__ gt_labels,
    const float* __restrict__ gt_bboxes, const unsigned int* __restrict__ mask,
    float* __restrict__ out) {
    int idx = blockIdx.x * THREADS + threadIdx.x;
    if (idx >= BATCH * NA) return;
    int b = idx / NA;

    unsigned msk = mask[idx];
    int tgt = msk ? (__ffs(msk) - 1) : 0;   // argmax over gt axis = first set bit
    float4 gb = ((const float4*)gt_bboxes)[b * NMAX + tgt];
    int lbl = gt_labels[b * NMAX + tgt];
    float4 p = ((const float4*)pd_bboxes)[idx];

    float sum = 0.0f;
    int cnt = 0;
    unsigned mm = msk;
    while (mm) {                             // ascending gt order = JAX sum order
        int i = __ffs(mm) - 1;
        mm &= mm - 1;
        float4 g = ((const float4*)gt_bboxes)[b * NMAX + i];
        sum += ciou_f(g.x, g.y, g.z, g.w, p.x, p.y, p.z, p.w);
        cnt++;
    }
    float po = fminf(fmaxf(sum / ((float)cnt + 1e-9f), 0.0f), 1.0f);

    bool fg = (msk != 0);
    out[idx] = fg ? (float)lbl : 80.0f;                       // target_labels
    ((float4*)(out + OFF_BOX))[idx] = gb;                     // target_bboxes
    if (fg) out[OFF_SCR + (size_t)idx * NC + lbl] = po;       // target_scores (rest zeroed)
    out[OFF_FG + idx]  = fg ? 1.0f : 0.0f;                    // fg_mask
    out[OFF_TGT + idx] = (float)tgt;                          // target_gt_idx
}

extern "C" void kernel_launch(void* const* d_in, const int* in_sizes, int n_in,
                              void* d_out, int out_size, void* d_ws, size_t ws_size,
                              hipStream_t stream) {
    const float* pd_scores = (const float*)d_in[0];
    const float* pd_bboxes = (const float*)d_in[1];
    // d_in[2] anc_points: unused by reference
    const int*   gt_labels = (const int*)d_in[3];
    const float* gt_bboxes = (const float*)d_in[4];
    // d_in[5] mask_gt: unused by reference (all ones)

    float* out = (float*)d_out;
    unsigned int* mask = (unsigned int*)d_ws;

    hipMemsetAsync(d_ws, 0, (size_t)BATCH * NA * sizeof(unsigned int), stream);
    hipMemsetAsync(d_out, 0, (size_t)out_size * sizeof(float), stream);

    topk_kernel<<<BATCH * NMAX, THREADS, 0, stream>>>(pd_scores, pd_bboxes,
                                                      gt_labels, gt_bboxes, mask);
    assign_kernel<<<(BATCH * NA + THREADS - 1) / THREADS, THREADS, 0, stream>>>(
        pd_bboxes, gt_labels, gt_bboxes, mask, out);
}

// Round 2
// 188.665 us; speedup vs baseline: 1.1141x; 1.1141x over previous
//
#include <hip/hip_runtime.h>
#include <math.h>

#define BATCH 32
#define NA 8400
#define NMAX 32
#define NC 80
#define TOPK 13
#define THREADS 256
#define NPT 33  // ceil(8400/256)

// flat output offsets (elements)
#define OFF_BOX 268800
#define OFF_SCR 1344000
#define OFF_FG  22848000
#define OFF_TGT 23116800
#define SCR_ELEMS (OFF_FG - OFF_SCR)   // 21,504,000

__device__ __forceinline__ float ciou_f(float gx1, float gy1, float gx2, float gy2,
                                        float px1, float py1, float px2, float py2) {
    const float eps = 1e-7f;
    float iw = fmaxf(fminf(gx2, px2) - fmaxf(gx1, px1), 0.0f);
    float ih = fmaxf(fminf(gy2, py2) - fmaxf(gy1, py1), 0.0f);
    float inter = iw * ih;
    float w1 = gx2 - gx1, h1 = gy2 - gy1 + eps;
    float w2 = px2 - px1, h2 = py2 - py1 + eps;
    float uni = w1 * h1 + w2 * h2 - inter + eps;
    float iou = inter / uni;
    float cw = fmaxf(gx2, px2) - fminf(gx1, px1);
    float ch = fmaxf(gy2, py2) - fminf(gy1, py1);
    float c2 = cw * cw + ch * ch + eps;
    float dx = px1 + px2 - gx1 - gx2;
    float dy = py1 + py2 - gy1 - gy2;
    float rho2 = (dx * dx + dy * dy) / 4.0f;
    float dd = atanf(w2 / h2) - atanf(w1 / h1);
    float v = (float)(4.0 / (M_PI * M_PI)) * dd * dd;
    float alpha = v / (v - iou + (1.0f + eps));
    return iou - (rho2 / c2 + v * alpha);
}

// Per-anchor metric computation. grid = (ceil(NA/256), BATCH). Each thread owns
// one anchor, loops over the 32 GTs (GT data staged in LDS), writes
// met[b][gt][a] coalesced. Arithmetic order matches ciou_f exactly (only the
// computation *site* of gt-invariant terms moved), so values are bit-identical.
__global__ __launch_bounds__(THREADS) void metric_kernel(
    const float* __restrict__ pd_scores, const float* __restrict__ pd_bboxes,
    const int* __restrict__ gt_labels, const float* __restrict__ gt_bboxes,
    float* __restrict__ met) {
    const int b = blockIdx.y;
    const int a = blockIdx.x * THREADS + threadIdx.x;
    const float eps = 1e-7f;

    __shared__ float sgx1[NMAX], sgy1[NMAX], sgx2[NMAX], sgy2[NMAX];
    __shared__ float sa1[NMAX], sat1[NMAX];
    __shared__ int   slbl[NMAX];
    if (threadIdx.x < NMAX) {
        float4 g = ((const float4*)gt_bboxes)[b * NMAX + threadIdx.x];
        float w1 = g.z - g.x, h1 = g.w - g.y + eps;
        sgx1[threadIdx.x] = g.x; sgy1[threadIdx.x] = g.y;
        sgx2[threadIdx.x] = g.z; sgy2[threadIdx.x] = g.w;
        sa1[threadIdx.x]  = w1 * h1;
        sat1[threadIdx.x] = atanf(w1 / h1);
        slbl[threadIdx.x] = gt_labels[b * NMAX + threadIdx.x];
    }
    __syncthreads();
    if (a >= NA) return;

    float4 p = ((const float4*)pd_bboxes)[(size_t)b * NA + a];
    float w2 = p.z - p.x, h2 = p.w - p.y + eps;
    float a2  = w2 * h2;
    float at2 = atanf(w2 / h2);
    const float* srec = pd_scores + ((size_t)b * NA + a) * NC;

#pragma unroll 8
    for (int gi = 0; gi < NMAX; gi++) {
        float gx1 = sgx1[gi], gy1 = sgy1[gi], gx2 = sgx2[gi], gy2 = sgy2[gi];
        float iw = fmaxf(fminf(gx2, p.z) - fmaxf(gx1, p.x), 0.0f);
        float ih = fmaxf(fminf(gy2, p.w) - fmaxf(gy1, p.y), 0.0f);
        float inter = iw * ih;
        float uni = sa1[gi] + a2 - inter + eps;
        float iou = inter / uni;
        float cw = fmaxf(gx2, p.z) - fminf(gx1, p.x);
        float ch = fmaxf(gy2, p.w) - fminf(gy1, p.y);
        float c2 = cw * cw + ch * ch + eps;
        float dx = p.x + p.z - gx1 - gx2;
        float dy = p.y + p.w - gy1 - gy2;
        float rho2 = (dx * dx + dy * dy) / 4.0f;
        float dd = at2 - sat1[gi];
        float v = (float)(4.0 / (M_PI * M_PI)) * dd * dd;
        float alpha = v / (v - iou + (1.0f + eps));
        float ov = iou - (rho2 / c2 + v * alpha);
        float sc = srec[slbl[gi]];                  // L1-resident after first touch
        float ov2 = ov * ov;
        met[((size_t)b * NMAX + gi) * NA + a] = sc * (ov2 * ov2 * ov2);
    }
}

// One block per (b, gt): top-13 selection over precomputed metrics (coalesced
// reads), tie-break lower anchor index (matches lax.top_k). ORs bit gi into mask.
__global__ __launch_bounds__(THREADS) void topk_kernel(
    const float* __restrict__ met, unsigned int* __restrict__ mask) {
    const int tid = threadIdx.x;
    const int bid = blockIdx.x;
    const int b  = bid >> 5;
    const int gi = bid & 31;
    const float* mrow = met + ((size_t)b * NMAX + gi) * NA;

    float m[NPT];
#pragma unroll
    for (int j = 0; j < NPT; j++) {
        int a = j * THREADS + tid;
        m[j] = (a < NA) ? mrow[a] : -INFINITY;
    }

    __shared__ float sv[4];
    __shared__ int   sa[4];
    __shared__ float swv;
    __shared__ int   swa;

    float wv = INFINITY;   // last selected winner in (value desc, index asc) order
    int   wa = -1;

    for (int k = 0; k < TOPK; k++) {
        float bv = -INFINITY;
        int   ba = 0x7FFFFFFF;
#pragma unroll
        for (int j = 0; j < NPT; j++) {
            int a = j * THREADS + tid;
            float v = m[j];
            bool below_win = (v < wv) || (v == wv && a > wa);
            bool beats     = (v > bv) || (v == bv && a < ba);
            if (below_win && beats) { bv = v; ba = a; }
        }
        float v = bv; int a = ba;
        for (int off = 32; off > 0; off >>= 1) {
            float ov = __shfl_down(v, off);
            int   oa = __shfl_down(a, off);
            if (ov > v || (ov == v && oa < a)) { v = ov; a = oa; }
        }
        if ((tid & 63) == 0) { sv[tid >> 6] = v; sa[tid >> 6] = a; }
        __syncthreads();
        if (tid == 0) {
            float fv = sv[0]; int fa = sa[0];
            for (int w = 1; w < 4; w++)
                if (sv[w] > fv || (sv[w] == fv && sa[w] < fa)) { fv = sv[w]; fa = sa[w]; }
            swv = fv; swa = fa;
            atomicOr(&mask[(size_t)b * NA + fa], 1u << gi);
        }
        __syncthreads();
        wv = swv; wa = swa;
    }
}

// One thread per (b, anchor): resolve assignment + write all five outputs.
__global__ __launch_bounds__(THREADS) void assign_kernel(
    const float* __restrict__ pd_bboxes, const int* __restrict__ gt_labels,
    const float* __restrict__ gt_bboxes, const unsigned int* __restrict__ mask,
    float* __restrict__ out) {
    int idx = blockIdx.x * THREADS + threadIdx.x;
    if (idx >= BATCH * NA) return;
    int b = idx / NA;

    unsigned msk = mask[idx];
    int tgt = msk ? (__ffs(msk) - 1) : 0;   // argmax over gt axis = first set bit
    float4 gb = ((const float4*)gt_bboxes)[b * NMAX + tgt];
    int lbl = gt_labels[b * NMAX + tgt];
    float4 p = ((const float4*)pd_bboxes)[idx];

    float sum = 0.0f;
    int cnt = 0;
    unsigned mm = msk;
    while (mm) {                             // ascending gt order = JAX sum order
        int i = __ffs(mm) - 1;
        mm &= mm - 1;
        float4 g = ((const float4*)gt_bboxes)[b * NMAX + i];
        sum += ciou_f(g.x, g.y, g.z, g.w, p.x, p.y, p.z, p.w);
        cnt++;
    }
    float po = fminf(fmaxf(sum / ((float)cnt + 1e-9f), 0.0f), 1.0f);

    bool fg = (msk != 0);
    out[idx] = fg ? (float)lbl : 80.0f;                       // target_labels
    ((float4*)(out + OFF_BOX))[idx] = gb;                     // target_bboxes
    if (fg) out[OFF_SCR + (size_t)idx * NC + lbl] = po;       // target_scores
    out[OFF_FG + idx]  = fg ? 1.0f : 0.0f;                    // fg_mask
    out[OFF_TGT + idx] = (float)tgt;                          // target_gt_idx
}

extern "C" void kernel_launch(void* const* d_in, const int* in_sizes, int n_in,
                              void* d_out, int out_size, void* d_ws, size_t ws_size,
                              hipStream_t stream) {
    const float* pd_scores = (const float*)d_in[0];
    const float* pd_bboxes = (const float*)d_in[1];
    // d_in[2] anc_points: unused by reference
    const int*   gt_labels = (const int*)d_in[3];
    const float* gt_bboxes = (const float*)d_in[4];
    // d_in[5] mask_gt: unused by reference (all ones)

    float* out = (float*)d_out;
    unsigned int* mask = (unsigned int*)d_ws;
    float* met = out + OFF_SCR;   // reuse the (later-zeroed) score plane as scratch

    hipMemsetAsync(d_ws, 0, (size_t)BATCH * NA * sizeof(unsigned int), stream);

    dim3 g1((NA + THREADS - 1) / THREADS, BATCH);
    metric_kernel<<<g1, THREADS, 0, stream>>>(pd_scores, pd_bboxes,
                                              gt_labels, gt_bboxes, met);
    topk_kernel<<<BATCH * NMAX, THREADS, 0, stream>>>(met, mask);

    // zero the score plane (also wipes the met scratch) before the scatter
    hipMemsetAsync(out + OFF_SCR, 0, (size_t)SCR_ELEMS * sizeof(float), stream);

    assign_kernel<<<(BATCH * NA + THREADS - 1) / THREADS, THREADS, 0, stream>>>(
        pd_bboxes, gt_labels, gt_bboxes, mask, out);
}

// Round 3
// 149.405 us; speedup vs baseline: 1.4068x; 1.2628x over previous
//
#include <hip/hip_runtime.h>
#include <math.h>

#define BATCH 32
#define NA 8400
#define NMAX 32
#define NC 80
#define TOPK 13
#define THREADS 256
#define NPT 33   // ceil(8400/256) for topk
#define TILE 64  // anchors per metric block
#define SSTRIDE 81  // LDS score row stride (odd*16+... -> conflict-free gather)

// flat output offsets (elements)
#define OFF_BOX 268800
#define OFF_SCR 1344000
#define OFF_FG  22848000
#define OFF_TGT 23116800

__device__ __forceinline__ float ciou_f(float gx1, float gy1, float gx2, float gy2,
                                        float px1, float py1, float px2, float py2) {
    const float eps = 1e-7f;
    float iw = fmaxf(fminf(gx2, px2) - fmaxf(gx1, px1), 0.0f);
    float ih = fmaxf(fminf(gy2, py2) - fmaxf(gy1, py1), 0.0f);
    float inter = iw * ih;
    float w1 = gx2 - gx1, h1 = gy2 - gy1 + eps;
    float w2 = px2 - px1, h2 = py2 - py1 + eps;
    float uni = w1 * h1 + w2 * h2 - inter + eps;
    float iou = inter / uni;
    float cw = fmaxf(gx2, px2) - fminf(gx1, px1);
    float ch = fmaxf(gy2, py2) - fminf(gy1, py1);
    float c2 = cw * cw + ch * ch + eps;
    float dx = px1 + px2 - gx1 - gx2;
    float dy = py1 + py2 - gy1 - gy2;
    float rho2 = (dx * dx + dy * dy) / 4.0f;
    float dd = atanf(w2 / h2) - atanf(w1 / h1);
    float v = (float)(4.0 / (M_PI * M_PI)) * dd * dd;
    float alpha = v / (v - iou + (1.0f + eps));
    return iou - (rho2 / c2 + v * alpha);
}

// grid = (ceil(NA/TILE), BATCH). Stage 64 full score records + 64 pd boxes in
// LDS (coalesced, each HBM line fetched once); then 4 gt-groups x 64 lanes
// compute all 32 metrics per anchor from LDS. Arithmetic order identical to
// ciou_f (gt/anchor-invariant terms only moved), so values are bit-identical.
__global__ __launch_bounds__(THREADS) void metric_kernel(
    const float* __restrict__ pd_scores, const float* __restrict__ pd_bboxes,
    const int* __restrict__ gt_labels, const float* __restrict__ gt_bboxes,
    float* __restrict__ met) {
    const int b = blockIdx.y;
    const int abase = blockIdx.x * TILE;
    const int tid = threadIdx.x;
    const int na_tile = min(TILE, NA - abase);
    const float eps = 1e-7f;

    __shared__ float ssc[TILE][SSTRIDE];
    __shared__ float4 spbox[TILE];
    __shared__ float sgx1[NMAX], sgy1[NMAX], sgx2[NMAX], sgy2[NMAX];
    __shared__ float sa1[NMAX], sat1[NMAX];
    __shared__ int   slbl[NMAX];

    if (tid < NMAX) {
        float4 g = ((const float4*)gt_bboxes)[b * NMAX + tid];
        float w1 = g.z - g.x, h1 = g.w - g.y + eps;
        sgx1[tid] = g.x; sgy1[tid] = g.y; sgx2[tid] = g.z; sgy2[tid] = g.w;
        sa1[tid]  = w1 * h1;
        sat1[tid] = atanf(w1 / h1);
        slbl[tid] = gt_labels[b * NMAX + tid];
    } else if (tid >= 64 && tid < 64 + TILE) {
        int al = tid - 64;
        if (al < na_tile)
            spbox[al] = ((const float4*)pd_bboxes)[(size_t)b * NA + abase + al];
    }

    // stage score records: na_tile*20 float4s, coalesced
    const float4* srec4 = (const float4*)(pd_scores + ((size_t)b * NA + abase) * NC);
    const int nf4 = na_tile * 20;
#pragma unroll
    for (int i = 0; i < 5; i++) {
        int f = tid + i * THREADS;
        if (f < nf4) {
            float4 v = srec4[f];
            int a = f / 20, c = f % 20;
            float* d = &ssc[a][c * 4];
            d[0] = v.x; d[1] = v.y; d[2] = v.z; d[3] = v.w;
        }
    }
    __syncthreads();

    const int al = tid & 63;
    const int gbase = (tid >> 6) * 8;   // 4 groups x 8 gts
    if (al >= na_tile) return;

    float4 p = spbox[al];
    float w2 = p.z - p.x, h2 = p.w - p.y + eps;
    float a2  = w2 * h2;
    float at2 = atanf(w2 / h2);
    const size_t abs_a = (size_t)abase + al;

#pragma unroll
    for (int k = 0; k < 8; k++) {
        int gi = gbase + k;
        float gx1 = sgx1[gi], gy1 = sgy1[gi], gx2 = sgx2[gi], gy2 = sgy2[gi];
        float iw = fmaxf(fminf(gx2, p.z) - fmaxf(gx1, p.x), 0.0f);
        float ih = fmaxf(fminf(gy2, p.w) - fmaxf(gy1, p.y), 0.0f);
        float inter = iw * ih;
        float uni = sa1[gi] + a2 - inter + eps;
        float iou = inter / uni;
        float cw = fmaxf(gx2, p.z) - fminf(gx1, p.x);
        float ch = fmaxf(gy2, p.w) - fminf(gy1, p.y);
        float c2 = cw * cw + ch * ch + eps;
        float dx = p.x + p.z - gx1 - gx2;
        float dy = p.y + p.w - gy1 - gy2;
        float rho2 = (dx * dx + dy * dy) / 4.0f;
        float dd = at2 - sat1[gi];
        float v = (float)(4.0 / (M_PI * M_PI)) * dd * dd;
        float alpha = v / (v - iou + (1.0f + eps));
        float ov = iou - (rho2 / c2 + v * alpha);
        float sc = ssc[al][slbl[gi]];       // bank-free: (81*lane+lbl)%32 spans all banks
        float ov2 = ov * ov;
        met[((size_t)b * NMAX + gi) * NA + abs_a] = sc * (ov2 * ov2 * ov2);
    }
}

// One block per (b, gt): top-13 selection over precomputed metrics (coalesced
// reads), tie-break lower anchor index (matches lax.top_k). ORs bit gi into mask.
__global__ __launch_bounds__(THREADS) void topk_kernel(
    const float* __restrict__ met, unsigned int* __restrict__ mask) {
    const int tid = threadIdx.x;
    const int bid = blockIdx.x;
    const int b  = bid >> 5;
    const int gi = bid & 31;
    const float* mrow = met + ((size_t)b * NMAX + gi) * NA;

    float m[NPT];
#pragma unroll
    for (int j = 0; j < NPT; j++) {
        int a = j * THREADS + tid;
        m[j] = (a < NA) ? mrow[a] : -INFINITY;
    }

    __shared__ float sv[4];
    __shared__ int   sa[4];
    __shared__ float swv;
    __shared__ int   swa;

    float wv = INFINITY;   // last selected winner in (value desc, index asc) order
    int   wa = -1;

    for (int k = 0; k < TOPK; k++) {
        float bv = -INFINITY;
        int   ba = 0x7FFFFFFF;
#pragma unroll
        for (int j = 0; j < NPT; j++) {
            int a = j * THREADS + tid;
            float v = m[j];
            bool below_win = (v < wv) || (v == wv && a > wa);
            bool beats     = (v > bv) || (v == bv && a < ba);
            if (below_win && beats) { bv = v; ba = a; }
        }
        float v = bv; int a = ba;
        for (int off = 32; off > 0; off >>= 1) {
            float ov = __shfl_down(v, off);
            int   oa = __shfl_down(a, off);
            if (ov > v || (ov == v && oa < a)) { v = ov; a = oa; }
        }
        if ((tid & 63) == 0) { sv[tid >> 6] = v; sa[tid >> 6] = a; }
        __syncthreads();
        if (tid == 0) {
            float fv = sv[0]; int fa = sa[0];
            for (int w = 1; w < 4; w++)
                if (sv[w] > fv || (sv[w] == fv && sa[w] < fa)) { fv = sv[w]; fa = sa[w]; }
            swv = fv; swa = fa;
            atomicOr(&mask[(size_t)b * NA + fa], 1u << gi);
        }
        __syncthreads();
        wv = swv; wa = swa;
    }
}

// One thread per (b, anchor): resolve assignment + write all five outputs,
// including the anchor's FULL 80-float one-hot score row (no separate memset).
__global__ __launch_bounds__(THREADS) void assign_kernel(
    const float* __restrict__ pd_bboxes, const int* __restrict__ gt_labels,
    const float* __restrict__ gt_bboxes, const unsigned int* __restrict__ mask,
    float* __restrict__ out) {
    int idx = blockIdx.x * THREADS + threadIdx.x;
    if (idx >= BATCH * NA) return;
    int b = idx / NA;

    unsigned msk = mask[idx];
    int tgt = msk ? (__ffs(msk) - 1) : 0;   // argmax over gt axis = first set bit
    float4 gb = ((const float4*)gt_bboxes)[b * NMAX + tgt];
    int lbl = gt_labels[b * NMAX + tgt];
    float4 p = ((const float4*)pd_bboxes)[idx];

    float sum = 0.0f;
    int cnt = 0;
    unsigned mm = msk;
    while (mm) {                             // ascending gt order = JAX sum order
        int i = __ffs(mm) - 1;
        mm &= mm - 1;
        float4 g = ((const float4*)gt_bboxes)[b * NMAX + i];
        sum += ciou_f(g.x, g.y, g.z, g.w, p.x, p.y, p.z, p.w);
        cnt++;
    }
    float po = fminf(fmaxf(sum / ((float)cnt + 1e-9f), 0.0f), 1.0f);

    bool fg = (msk != 0);
    out[idx] = fg ? (float)lbl : 80.0f;                       // target_labels
    ((float4*)(out + OFF_BOX))[idx] = gb;                     // target_bboxes
    out[OFF_FG + idx]  = fg ? 1.0f : 0.0f;                    // fg_mask
    out[OFF_TGT + idx] = (float)tgt;                          // target_gt_idx

    // full one-hot score row (overwrites met scratch living in this plane)
    float4* orow = (float4*)(out + OFF_SCR + (size_t)idx * NC);
    int lc = lbl >> 2, lj = lbl & 3;
#pragma unroll
    for (int c = 0; c < 20; c++) {
        float4 z = make_float4(0.f, 0.f, 0.f, 0.f);
        if (fg && c == lc) ((float*)&z)[lj] = po;
        orow[c] = z;
    }
}

extern "C" void kernel_launch(void* const* d_in, const int* in_sizes, int n_in,
                              void* d_out, int out_size, void* d_ws, size_t ws_size,
                              hipStream_t stream) {
    const float* pd_scores = (const float*)d_in[0];
    const float* pd_bboxes = (const float*)d_in[1];
    // d_in[2] anc_points: unused by reference
    const int*   gt_labels = (const int*)d_in[3];
    const float* gt_bboxes = (const float*)d_in[4];
    // d_in[5] mask_gt: unused by reference (all ones)

    float* out = (float*)d_out;
    unsigned int* mask = (unsigned int*)d_ws;
    float* met = out + OFF_SCR;   // score plane doubles as met scratch

    hipMemsetAsync(d_ws, 0, (size_t)BATCH * NA * sizeof(unsigned int), stream);

    dim3 g1((NA + TILE - 1) / TILE, BATCH);
    metric_kernel<<<g1, THREADS, 0, stream>>>(pd_scores, pd_bboxes,
                                              gt_labels, gt_bboxes, met);
    topk_kernel<<<BATCH * NMAX, THREADS, 0, stream>>>(met, mask);
    assign_kernel<<<(BATCH * NA + THREADS - 1) / THREADS, THREADS, 0, stream>>>(
        pd_bboxes, gt_labels, gt_bboxes, mask, out);
}

// Round 4
// 128.032 us; speedup vs baseline: 1.6416x; 1.1669x over previous
//
#include <hip/hip_runtime.h>
#include <math.h>

#define BATCH 32
#define NA 8400
#define NMAX 32
#define NC 80
#define TOPK 13
#define THREADS 256
#define NPT 33   // ceil(8400/256) for topk
#define TILE 64  // anchors per metric block
#define SSTRIDE 81  // LDS score row stride (odd -> conflict-free gather)

// flat output offsets (elements)
#define OFF_BOX 268800
#define OFF_SCR 1344000
#define OFF_FG  22848000
#define OFF_TGT 23116800

__device__ __forceinline__ float ciou_f(float gx1, float gy1, float gx2, float gy2,
                                        float px1, float py1, float px2, float py2) {
    const float eps = 1e-7f;
    float iw = fmaxf(fminf(gx2, px2) - fmaxf(gx1, px1), 0.0f);
    float ih = fmaxf(fminf(gy2, py2) - fmaxf(gy1, py1), 0.0f);
    float inter = iw * ih;
    float w1 = gx2 - gx1, h1 = gy2 - gy1 + eps;
    float w2 = px2 - px1, h2 = py2 - py1 + eps;
    float uni = w1 * h1 + w2 * h2 - inter + eps;
    float iou = inter / uni;
    float cw = fmaxf(gx2, px2) - fminf(gx1, px1);
    float ch = fmaxf(gy2, py2) - fminf(gy1, py1);
    float c2 = cw * cw + ch * ch + eps;
    float dx = px1 + px2 - gx1 - gx2;
    float dy = py1 + py2 - gy1 - gy2;
    float rho2 = (dx * dx + dy * dy) / 4.0f;
    float dd = atanf(w2 / h2) - atanf(w1 / h1);
    float v = (float)(4.0 / (M_PI * M_PI)) * dd * dd;
    float alpha = v / (v - iou + (1.0f + eps));
    return iou - (rho2 / c2 + v * alpha);
}

// grid = (ceil(NA/TILE), BATCH). Stage 64 full score records + 64 pd boxes in
// LDS (coalesced, each HBM line fetched once); then 4 gt-groups x 64 lanes
// compute all 32 metrics per anchor from LDS. Arithmetic order identical to
// ciou_f (gt/anchor-invariant terms only moved), so values are bit-identical.
__global__ __launch_bounds__(THREADS) void metric_kernel(
    const float* __restrict__ pd_scores, const float* __restrict__ pd_bboxes,
    const int* __restrict__ gt_labels, const float* __restrict__ gt_bboxes,
    float* __restrict__ met) {
    const int b = blockIdx.y;
    const int abase = blockIdx.x * TILE;
    const int tid = threadIdx.x;
    const int na_tile = min(TILE, NA - abase);
    const float eps = 1e-7f;

    __shared__ float ssc[TILE][SSTRIDE];
    __shared__ float4 spbox[TILE];
    __shared__ float sgx1[NMAX], sgy1[NMAX], sgx2[NMAX], sgy2[NMAX];
    __shared__ float sa1[NMAX], sat1[NMAX];
    __shared__ int   slbl[NMAX];

    if (tid < NMAX) {
        float4 g = ((const float4*)gt_bboxes)[b * NMAX + tid];
        float w1 = g.z - g.x, h1 = g.w - g.y + eps;
        sgx1[tid] = g.x; sgy1[tid] = g.y; sgx2[tid] = g.z; sgy2[tid] = g.w;
        sa1[tid]  = w1 * h1;
        sat1[tid] = atanf(w1 / h1);
        slbl[tid] = gt_labels[b * NMAX + tid];
    } else if (tid >= 64 && tid < 64 + TILE) {
        int al = tid - 64;
        if (al < na_tile)
            spbox[al] = ((const float4*)pd_bboxes)[(size_t)b * NA + abase + al];
    }

    // stage score records: na_tile*20 float4s, coalesced
    const float4* srec4 = (const float4*)(pd_scores + ((size_t)b * NA + abase) * NC);
    const int nf4 = na_tile * 20;
#pragma unroll
    for (int i = 0; i < 5; i++) {
        int f = tid + i * THREADS;
        if (f < nf4) {
            float4 v = srec4[f];
            int a = f / 20, c = f % 20;
            float* d = &ssc[a][c * 4];
            d[0] = v.x; d[1] = v.y; d[2] = v.z; d[3] = v.w;
        }
    }
    __syncthreads();

    const int al = tid & 63;
    const int gbase = (tid >> 6) * 8;   // 4 groups x 8 gts
    if (al >= na_tile) return;

    float4 p = spbox[al];
    float w2 = p.z - p.x, h2 = p.w - p.y + eps;
    float a2  = w2 * h2;
    float at2 = atanf(w2 / h2);
    const size_t abs_a = (size_t)abase + al;

#pragma unroll
    for (int k = 0; k < 8; k++) {
        int gi = gbase + k;
        float gx1 = sgx1[gi], gy1 = sgy1[gi], gx2 = sgx2[gi], gy2 = sgy2[gi];
        float iw = fmaxf(fminf(gx2, p.z) - fmaxf(gx1, p.x), 0.0f);
        float ih = fmaxf(fminf(gy2, p.w) - fmaxf(gy1, p.y), 0.0f);
        float inter = iw * ih;
        float uni = sa1[gi] + a2 - inter + eps;
        float iou = inter / uni;
        float cw = fmaxf(gx2, p.z) - fminf(gx1, p.x);
        float ch = fmaxf(gy2, p.w) - fminf(gy1, p.y);
        float c2 = cw * cw + ch * ch + eps;
        float dx = p.x + p.z - gx1 - gx2;
        float dy = p.y + p.w - gy1 - gy2;
        float rho2 = (dx * dx + dy * dy) / 4.0f;
        float dd = at2 - sat1[gi];
        float v = (float)(4.0 / (M_PI * M_PI)) * dd * dd;
        float alpha = v / (v - iou + (1.0f + eps));
        float ov = iou - (rho2 / c2 + v * alpha);
        float sc = ssc[al][slbl[gi]];
        float ov2 = ov * ov;
        met[((size_t)b * NMAX + gi) * NA + abs_a] = sc * (ov2 * ov2 * ov2);
    }
}

// One block per (b, gt) row. Phase A: each wave finds the top-13 of its own
// 2112 elements barrier-free (per-lane top-2 cache + butterfly argmax; rare
// divergent rescan only when a lane wins twice). Phase B: wave 0 merges the
// 4x13 candidates and scatters atomicOr bits. ONE __syncthreads total.
// Tie-break everywhere: (value desc, index asc) — matches lax.top_k.
__global__ __launch_bounds__(THREADS) void topk_kernel(
    const float* __restrict__ met, unsigned int* __restrict__ mask) {
    const int tid  = threadIdx.x;
    const int lane = tid & 63;
    const int w    = tid >> 6;
    const int bid  = blockIdx.x;
    const int b  = bid >> 5;
    const int gi = bid & 31;
    const float* mrow = met + ((size_t)b * NMAX + gi) * NA;

    float m[NPT];
#pragma unroll
    for (int j = 0; j < NPT; j++) {
        int a = j * THREADS + tid;
        m[j] = (a < NA) ? mrow[a] : -INFINITY;
    }

    // per-lane top-2 cache
    float bv0 = -INFINITY, bv1 = -INFINITY;
    int   ba0 = 0x7FFFFFFF, ba1 = 0x7FFFFFFF;
#pragma unroll
    for (int j = 0; j < NPT; j++) {
        float v = m[j]; int a = j * THREADS + tid;
        bool beats0 = (v > bv0) || (v == bv0 && a < ba0);
        bool beats1 = (v > bv1) || (v == bv1 && a < ba1);
        if (beats0) { bv1 = bv0; ba1 = ba0; bv0 = v; ba0 = a; }
        else if (beats1) { bv1 = v; ba1 = a; }
    }
    bool valid1 = true;

    float rv = -INFINITY; int ra = 0x7FFFFFFF;   // lane k holds k-th wave winner
    for (int k = 0; k < TOPK; k++) {
        float v = bv0; int a = ba0;
#pragma unroll
        for (int s = 1; s < 64; s <<= 1) {
            float ov = __shfl_xor(v, s);
            int   oa = __shfl_xor(a, s);
            if (ov > v || (ov == v && oa < a)) { v = ov; a = oa; }
        }
        if (lane == k) { rv = v; ra = a; }
        if (ba0 == a) {            // unique owner (lanes own disjoint indices)
            if (valid1) { bv0 = bv1; ba0 = ba1; valid1 = false; }
            else {                 // rare: lane won >=2 times -> rescan below (v,a)
                float nv = -INFINITY; int na_ = 0x7FFFFFFF;
#pragma unroll
                for (int j = 0; j < NPT; j++) {
                    float mv = m[j]; int ma = j * THREADS + tid;
                    bool below = (mv < v) || (mv == v && ma > a);
                    bool beats = (mv > nv) || (mv == nv && ma < na_);
                    if (below && beats) { nv = mv; na_ = ma; }
                }
                bv0 = nv; ba0 = na_;
            }
        }
    }

    __shared__ float lv[4 * TOPK];
    __shared__ int   la[4 * TOPK];
    if (lane < TOPK) { lv[w * TOPK + lane] = rv; la[w * TOPK + lane] = ra; }
    __syncthreads();

    if (w == 0) {
        float v = (lane < 4 * TOPK) ? lv[lane] : -INFINITY;
        int   a = (lane < 4 * TOPK) ? la[lane] : 0x7FFFFFFF;
        for (int k = 0; k < TOPK; k++) {
            float wv = v; int wa = a;
#pragma unroll
            for (int s = 1; s < 64; s <<= 1) {
                float ov = __shfl_xor(wv, s);
                int   oa = __shfl_xor(wa, s);
                if (ov > wv || (ov == wv && oa < wa)) { wv = ov; wa = oa; }
            }
            if (lane == 0) atomicOr(&mask[(size_t)b * NA + wa], 1u << gi);
            if (a == wa) { v = -INFINITY; a = 0x7FFFFFFF; }  // consume
        }
    }
}

// One thread per (b, anchor): resolve assignment + write all five outputs,
// including the anchor's FULL 80-float one-hot score row (no separate memset).
__global__ __launch_bounds__(THREADS) void assign_kernel(
    const float* __restrict__ pd_bboxes, const int* __restrict__ gt_labels,
    const float* __restrict__ gt_bboxes, const unsigned int* __restrict__ mask,
    float* __restrict__ out) {
    int idx = blockIdx.x * THREADS + threadIdx.x;
    if (idx >= BATCH * NA) return;
    int b = idx / NA;

    unsigned msk = mask[idx];
    int tgt = msk ? (__ffs(msk) - 1) : 0;   // argmax over gt axis = first set bit
    float4 gb = ((const float4*)gt_bboxes)[b * NMAX + tgt];
    int lbl = gt_labels[b * NMAX + tgt];
    float4 p = ((const float4*)pd_bboxes)[idx];

    float sum = 0.0f;
    int cnt = 0;
    unsigned mm = msk;
    while (mm) {                             // ascending gt order = JAX sum order
        int i = __ffs(mm) - 1;
        mm &= mm - 1;
        float4 g = ((const float4*)gt_bboxes)[b * NMAX + i];
        sum += ciou_f(g.x, g.y, g.z, g.w, p.x, p.y, p.z, p.w);
        cnt++;
    }
    float po = fminf(fmaxf(sum / ((float)cnt + 1e-9f), 0.0f), 1.0f);

    bool fg = (msk != 0);
    out[idx] = fg ? (float)lbl : 80.0f;                       // target_labels
    ((float4*)(out + OFF_BOX))[idx] = gb;                     // target_bboxes
    out[OFF_FG + idx]  = fg ? 1.0f : 0.0f;                    // fg_mask
    out[OFF_TGT + idx] = (float)tgt;                          // target_gt_idx

    // full one-hot score row (overwrites met scratch living in this plane)
    float4* orow = (float4*)(out + OFF_SCR + (size_t)idx * NC);
    int lc = lbl >> 2, lj = lbl & 3;
#pragma unroll
    for (int c = 0; c < 20; c++) {
        float4 z = make_float4(0.f, 0.f, 0.f, 0.f);
        if (fg && c == lc) ((float*)&z)[lj] = po;
        orow[c] = z;
    }
}

extern "C" void kernel_launch(void* const* d_in, const int* in_sizes, int n_in,
                              void* d_out, int out_size, void* d_ws, size_t ws_size,
                              hipStream_t stream) {
    const float* pd_scores = (const float*)d_in[0];
    const float* pd_bboxes = (const float*)d_in[1];
    // d_in[2] anc_points: unused by reference
    const int*   gt_labels = (const int*)d_in[3];
    const float* gt_bboxes = (const float*)d_in[4];
    // d_in[5] mask_gt: unused by reference (all ones)

    float* out = (float*)d_out;
    unsigned int* mask = (unsigned int*)d_ws;
    float* met = out + OFF_SCR;   // score plane doubles as met scratch

    hipMemsetAsync(d_ws, 0, (size_t)BATCH * NA * sizeof(unsigned int), stream);

    dim3 g1((NA + TILE - 1) / TILE, BATCH);
    metric_kernel<<<g1, THREADS, 0, stream>>>(pd_scores, pd_bboxes,
                                              gt_labels, gt_bboxes, met);
    topk_kernel<<<BATCH * NMAX, THREADS, 0, stream>>>(met, mask);
    assign_kernel<<<(BATCH * NA + THREADS - 1) / THREADS, THREADS, 0, stream>>>(
        pd_bboxes, gt_labels, gt_bboxes, mask, out);
}

// Round 5
// 95.418 us; speedup vs baseline: 2.2028x; 1.3418x over previous
//
#include <hip/hip_runtime.h>
#include <math.h>

#define BATCH 32
#define NA 8400
#define NMAX 32
#define NC 80
#define TOPK 13
#define THREADS 256
#define NPT 33   // ceil(8400/256) for topk
#define TILE 64  // anchors per metric block
#define SSTRIDE 81  // LDS score row stride (odd -> conflict-free gather)

// flat output offsets (elements)
#define OFF_BOX 268800
#define OFF_SCR 1344000
#define OFF_FG  22848000
#define OFF_TGT 23116800

__device__ __forceinline__ float ciou_f(float gx1, float gy1, float gx2, float gy2,
                                        float px1, float py1, float px2, float py2) {
    const float eps = 1e-7f;
    float iw = fmaxf(fminf(gx2, px2) - fmaxf(gx1, px1), 0.0f);
    float ih = fmaxf(fminf(gy2, py2) - fmaxf(gy1, py1), 0.0f);
    float inter = iw * ih;
    float w1 = gx2 - gx1, h1 = gy2 - gy1 + eps;
    float w2 = px2 - px1, h2 = py2 - py1 + eps;
    float uni = w1 * h1 + w2 * h2 - inter + eps;
    float iou = inter / uni;
    float cw = fmaxf(gx2, px2) - fminf(gx1, px1);
    float ch = fmaxf(gy2, py2) - fminf(gy1, py1);
    float c2 = cw * cw + ch * ch + eps;
    float dx = px1 + px2 - gx1 - gx2;
    float dy = py1 + py2 - gy1 - gy2;
    float rho2 = (dx * dx + dy * dy) / 4.0f;
    float dd = atanf(w2 / h2) - atanf(w1 / h1);
    float v = (float)(4.0 / (M_PI * M_PI)) * dd * dd;
    float alpha = v / (v - iou + (1.0f + eps));
    return iou - (rho2 / c2 + v * alpha);
}

// grid = (ceil(NA/TILE), BATCH). Stage 64 full score records + 64 pd boxes in
// LDS (coalesced, each HBM line fetched once); then 4 gt-groups x 64 lanes
// compute all 32 metrics per anchor from LDS. Also zeroes this block's 64 mask
// words (replaces the separate memset dispatch; stream-ordered before topk).
__global__ __launch_bounds__(THREADS) void metric_kernel(
    const float* __restrict__ pd_scores, const float* __restrict__ pd_bboxes,
    const int* __restrict__ gt_labels, const float* __restrict__ gt_bboxes,
    float* __restrict__ met, unsigned int* __restrict__ mask) {
    const int b = blockIdx.y;
    const int abase = blockIdx.x * TILE;
    const int tid = threadIdx.x;
    const int na_tile = min(TILE, NA - abase);
    const float eps = 1e-7f;

    if (tid < na_tile) mask[(size_t)b * NA + abase + tid] = 0u;

    __shared__ float ssc[TILE][SSTRIDE];
    __shared__ float4 spbox[TILE];
    __shared__ float sgx1[NMAX], sgy1[NMAX], sgx2[NMAX], sgy2[NMAX];
    __shared__ float sa1[NMAX], sat1[NMAX];
    __shared__ int   slbl[NMAX];

    if (tid < NMAX) {
        float4 g = ((const float4*)gt_bboxes)[b * NMAX + tid];
        float w1 = g.z - g.x, h1 = g.w - g.y + eps;
        sgx1[tid] = g.x; sgy1[tid] = g.y; sgx2[tid] = g.z; sgy2[tid] = g.w;
        sa1[tid]  = w1 * h1;
        sat1[tid] = atanf(w1 / h1);
        slbl[tid] = gt_labels[b * NMAX + tid];
    } else if (tid >= 64 && tid < 64 + TILE) {
        int al = tid - 64;
        if (al < na_tile)
            spbox[al] = ((const float4*)pd_bboxes)[(size_t)b * NA + abase + al];
    }

    // stage score records: na_tile*20 float4s, coalesced
    const float4* srec4 = (const float4*)(pd_scores + ((size_t)b * NA + abase) * NC);
    const int nf4 = na_tile * 20;
#pragma unroll
    for (int i = 0; i < 5; i++) {
        int f = tid + i * THREADS;
        if (f < nf4) {
            float4 v = srec4[f];
            int a = f / 20, c = f % 20;
            float* d = &ssc[a][c * 4];
            d[0] = v.x; d[1] = v.y; d[2] = v.z; d[3] = v.w;
        }
    }
    __syncthreads();

    const int al = tid & 63;
    const int gbase = (tid >> 6) * 8;   // 4 groups x 8 gts
    if (al >= na_tile) return;

    float4 p = spbox[al];
    float w2 = p.z - p.x, h2 = p.w - p.y + eps;
    float a2  = w2 * h2;
    float at2 = atanf(w2 / h2);
    const size_t abs_a = (size_t)abase + al;

#pragma unroll
    for (int k = 0; k < 8; k++) {
        int gi = gbase + k;
        float gx1 = sgx1[gi], gy1 = sgy1[gi], gx2 = sgx2[gi], gy2 = sgy2[gi];
        float iw = fmaxf(fminf(gx2, p.z) - fmaxf(gx1, p.x), 0.0f);
        float ih = fmaxf(fminf(gy2, p.w) - fmaxf(gy1, p.y), 0.0f);
        float inter = iw * ih;
        float uni = sa1[gi] + a2 - inter + eps;
        float iou = inter / uni;
        float cw = fmaxf(gx2, p.z) - fminf(gx1, p.x);
        float ch = fmaxf(gy2, p.w) - fminf(gy1, p.y);
        float c2 = cw * cw + ch * ch + eps;
        float dx = p.x + p.z - gx1 - gx2;
        float dy = p.y + p.w - gy1 - gy2;
        float rho2 = (dx * dx + dy * dy) / 4.0f;
        float dd = at2 - sat1[gi];
        float v = (float)(4.0 / (M_PI * M_PI)) * dd * dd;
        float alpha = v / (v - iou + (1.0f + eps));
        float ov = iou - (rho2 / c2 + v * alpha);
        float sc = ssc[al][slbl[gi]];
        float ov2 = ov * ov;
        met[((size_t)b * NMAX + gi) * NA + abs_a] = sc * (ov2 * ov2 * ov2);
    }
}

// One block per (b, gt) row. Phase A: each wave finds the top-13 of its own
// 2112 elements barrier-free (per-lane top-2 cache + butterfly argmax; rare
// divergent rescan only when a lane wins twice). Phase B: wave 0 merges the
// 4x13 candidates and scatters atomicOr bits. ONE __syncthreads total.
// Tie-break everywhere: (value desc, index asc) — matches lax.top_k.
__global__ __launch_bounds__(THREADS) void topk_kernel(
    const float* __restrict__ met, unsigned int* __restrict__ mask) {
    const int tid  = threadIdx.x;
    const int lane = tid & 63;
    const int w    = tid >> 6;
    const int bid  = blockIdx.x;
    const int b  = bid >> 5;
    const int gi = bid & 31;
    const float* mrow = met + ((size_t)b * NMAX + gi) * NA;

    float m[NPT];
#pragma unroll
    for (int j = 0; j < NPT; j++) {
        int a = j * THREADS + tid;
        m[j] = (a < NA) ? mrow[a] : -INFINITY;
    }

    // per-lane top-2 cache
    float bv0 = -INFINITY, bv1 = -INFINITY;
    int   ba0 = 0x7FFFFFFF, ba1 = 0x7FFFFFFF;
#pragma unroll
    for (int j = 0; j < NPT; j++) {
        float v = m[j]; int a = j * THREADS + tid;
        bool beats0 = (v > bv0) || (v == bv0 && a < ba0);
        bool beats1 = (v > bv1) || (v == bv1 && a < ba1);
        if (beats0) { bv1 = bv0; ba1 = ba0; bv0 = v; ba0 = a; }
        else if (beats1) { bv1 = v; ba1 = a; }
    }
    bool valid1 = true;

    float rv = -INFINITY; int ra = 0x7FFFFFFF;   // lane k holds k-th wave winner
    for (int k = 0; k < TOPK; k++) {
        float v = bv0; int a = ba0;
#pragma unroll
        for (int s = 1; s < 64; s <<= 1) {
            float ov = __shfl_xor(v, s);
            int   oa = __shfl_xor(a, s);
            if (ov > v || (ov == v && oa < a)) { v = ov; a = oa; }
        }
        if (lane == k) { rv = v; ra = a; }
        if (ba0 == a) {            // unique owner (lanes own disjoint indices)
            if (valid1) { bv0 = bv1; ba0 = ba1; valid1 = false; }
            else {                 // rare: lane won >=2 times -> rescan below (v,a)
                float nv = -INFINITY; int na_ = 0x7FFFFFFF;
#pragma unroll
                for (int j = 0; j < NPT; j++) {
                    float mv = m[j]; int ma = j * THREADS + tid;
                    bool below = (mv < v) || (mv == v && ma > a);
                    bool beats = (mv > nv) || (mv == nv && ma < na_);
                    if (below && beats) { nv = mv; na_ = ma; }
                }
                bv0 = nv; ba0 = na_;
            }
        }
    }

    __shared__ float lv[4 * TOPK];
    __shared__ int   la[4 * TOPK];
    if (lane < TOPK) { lv[w * TOPK + lane] = rv; la[w * TOPK + lane] = ra; }
    __syncthreads();

    if (w == 0) {
        float v = (lane < 4 * TOPK) ? lv[lane] : -INFINITY;
        int   a = (lane < 4 * TOPK) ? la[lane] : 0x7FFFFFFF;
        for (int k = 0; k < TOPK; k++) {
            float wv = v; int wa = a;
#pragma unroll
            for (int s = 1; s < 64; s <<= 1) {
                float ov = __shfl_xor(wv, s);
                int   oa = __shfl_xor(wa, s);
                if (ov > wv || (ov == wv && oa < wa)) { wv = ov; wa = oa; }
            }
            if (lane == 0) atomicOr(&mask[(size_t)b * NA + wa], 1u << gi);
            if (a == wa) { v = -INFINITY; a = 0x7FFFFFFF; }  // consume
        }
    }
}

// Fused assign + score writer. Block = 64 anchors (B*NA = 4200*64 exactly).
// Lanes 0..63 resolve the assignment (same arithmetic as before -> bit-identical),
// stash (po, label-or-neg) in LDS; then all 256 threads stream the 64x20 float4
// one-hot score rows with lane-consecutive addresses (fully coalesced).
__global__ __launch_bounds__(THREADS) void assign_score_kernel(
    const float* __restrict__ pd_bboxes, const int* __restrict__ gt_labels,
    const float* __restrict__ gt_bboxes, const unsigned int* __restrict__ mask,
    float* __restrict__ out) {
    const int tid = threadIdx.x;
    const int ab = blockIdx.x * 64;
    __shared__ float spo[64];
    __shared__ int   slb[64];   // label if fg else -1

    if (tid < 64) {
        int idx = ab + tid;
        int b = idx / NA;
        unsigned msk = mask[idx];
        int tgt = msk ? (__ffs(msk) - 1) : 0;   // argmax over gt = first set bit
        float4 gb = ((const float4*)gt_bboxes)[b * NMAX + tgt];
        int lbl = gt_labels[b * NMAX + tgt];
        float4 p = ((const float4*)pd_bboxes)[idx];

        float sum = 0.0f;
        int cnt = 0;
        unsigned mm = msk;
        while (mm) {                             // ascending gt order = JAX sum order
            int i = __ffs(mm) - 1;
            mm &= mm - 1;
            float4 g = ((const float4*)gt_bboxes)[b * NMAX + i];
            sum += ciou_f(g.x, g.y, g.z, g.w, p.x, p.y, p.z, p.w);
            cnt++;
        }
        float po = fminf(fmaxf(sum / ((float)cnt + 1e-9f), 0.0f), 1.0f);

        bool fg = (msk != 0);
        out[idx] = fg ? (float)lbl : 80.0f;                   // target_labels
        ((float4*)(out + OFF_BOX))[idx] = gb;                 // target_bboxes
        out[OFF_FG + idx]  = fg ? 1.0f : 0.0f;                // fg_mask
        out[OFF_TGT + idx] = (float)tgt;                      // target_gt_idx
        spo[tid] = po;
        slb[tid] = fg ? lbl : -1;
    }
    __syncthreads();

    float4* obase = (float4*)(out + OFF_SCR + (size_t)ab * NC);
#pragma unroll
    for (int i = 0; i < 5; i++) {
        int f = tid + i * THREADS;       // 0..1279, lane-consecutive
        int a = f / 20, c = f % 20;
        int lbl = slb[a];
        float4 z = make_float4(0.f, 0.f, 0.f, 0.f);
        if ((lbl >> 2) == c) ((float*)&z)[lbl & 3] = spo[a];
        obase[f] = z;
    }
}

extern "C" void kernel_launch(void* const* d_in, const int* in_sizes, int n_in,
                              void* d_out, int out_size, void* d_ws, size_t ws_size,
                              hipStream_t stream) {
    const float* pd_scores = (const float*)d_in[0];
    const float* pd_bboxes = (const float*)d_in[1];
    // d_in[2] anc_points: unused by reference
    const int*   gt_labels = (const int*)d_in[3];
    const float* gt_bboxes = (const float*)d_in[4];
    // d_in[5] mask_gt: unused by reference (all ones)

    float* out = (float*)d_out;
    unsigned int* mask = (unsigned int*)d_ws;
    float* met = out + OFF_SCR;   // score plane doubles as met scratch

    dim3 g1((NA + TILE - 1) / TILE, BATCH);
    metric_kernel<<<g1, THREADS, 0, stream>>>(pd_scores, pd_bboxes,
                                              gt_labels, gt_bboxes, met, mask);
    topk_kernel<<<BATCH * NMAX, THREADS, 0, stream>>>(met, mask);
    assign_score_kernel<<<BATCH * NA / 64, THREADS, 0, stream>>>(
        pd_bboxes, gt_labels, gt_bboxes, mask, out);
}

// Round 7
// 91.809 us; speedup vs baseline: 2.2893x; 1.0393x over previous
//
#include <hip/hip_runtime.h>
#include <math.h>

#define BATCH 32
#define NA 8400
#define NMAX 32
#define NC 80
#define TOPK 13
#define THREADS 256
#define NPT 33    // ceil(8400/256) for topk
#define TILE 128  // anchors per metric block
#define SSTRIDE 81  // LDS score row stride (odd -> conflict-free gather)

// flat output offsets (elements)
#define OFF_BOX 268800
#define OFF_SCR 1344000
#define OFF_FG  22848000
#define OFF_TGT 23116800

typedef float f32x4 __attribute__((ext_vector_type(4)));   // NT-store-compatible

__device__ __forceinline__ float ciou_f(float gx1, float gy1, float gx2, float gy2,
                                        float px1, float py1, float px2, float py2) {
    const float eps = 1e-7f;
    float iw = fmaxf(fminf(gx2, px2) - fmaxf(gx1, px1), 0.0f);
    float ih = fmaxf(fminf(gy2, py2) - fmaxf(gy1, py1), 0.0f);
    float inter = iw * ih;
    float w1 = gx2 - gx1, h1 = gy2 - gy1 + eps;
    float w2 = px2 - px1, h2 = py2 - py1 + eps;
    float uni = w1 * h1 + w2 * h2 - inter + eps;
    float iou = inter / uni;
    float cw = fmaxf(gx2, px2) - fminf(gx1, px1);
    float ch = fmaxf(gy2, py2) - fminf(gy1, py1);
    float c2 = cw * cw + ch * ch + eps;
    float dx = px1 + px2 - gx1 - gx2;
    float dy = py1 + py2 - gy1 - gy2;
    float rho2 = (dx * dx + dy * dy) / 4.0f;
    float dd = atanf(w2 / h2) - atanf(w1 / h1);
    float v = (float)(4.0 / (M_PI * M_PI)) * dd * dd;
    float alpha = v / (v - iou + (1.0f + eps));
    return iou - (rho2 / c2 + v * alpha);
}

// grid = (ceil(NA/TILE), BATCH), TILE=128. Stage 128 score records via explicit
// register staging (10 back-to-back float4 loads, then LDS writes) + 128 pd
// boxes; 2 gt-groups x 128 lanes compute 16 metrics each from LDS. Also zeroes
// this block's mask words (replaces memset dispatch). Arithmetic identical to
// ciou_f -> bit-identical metrics.
__global__ __launch_bounds__(THREADS, 2) void metric_kernel(
    const float* __restrict__ pd_scores, const float* __restrict__ pd_bboxes,
    const int* __restrict__ gt_labels, const float* __restrict__ gt_bboxes,
    float* __restrict__ met, unsigned int* __restrict__ mask) {
    const int b = blockIdx.y;
    const int abase = blockIdx.x * TILE;
    const int tid = threadIdx.x;
    const int na_tile = min(TILE, NA - abase);
    const float eps = 1e-7f;

    if (tid < na_tile) mask[(size_t)b * NA + abase + tid] = 0u;

    __shared__ float ssc[TILE][SSTRIDE];
    __shared__ float4 spbox[TILE];
    __shared__ float sgx1[NMAX], sgy1[NMAX], sgx2[NMAX], sgy2[NMAX];
    __shared__ float sa1[NMAX], sat1[NMAX];
    __shared__ int   slbl[NMAX];

    if (tid < NMAX) {
        float4 g = ((const float4*)gt_bboxes)[b * NMAX + tid];
        float w1 = g.z - g.x, h1 = g.w - g.y + eps;
        sgx1[tid] = g.x; sgy1[tid] = g.y; sgx2[tid] = g.z; sgy2[tid] = g.w;
        sa1[tid]  = w1 * h1;
        sat1[tid] = atanf(w1 / h1);
        slbl[tid] = gt_labels[b * NMAX + tid];
    } else if (tid >= 128) {
        int al = tid - 128;
        if (al < na_tile)
            spbox[al] = ((const float4*)pd_bboxes)[(size_t)b * NA + abase + al];
    }

    // register-staged score load: all loads issued before any LDS write
    const float4* srec4 = (const float4*)(pd_scores + ((size_t)b * NA + abase) * NC);
    const int nf4 = na_tile * 20;
    float4 r[10];
#pragma unroll
    for (int i = 0; i < 10; i++) {
        int f = tid + i * THREADS;
        if (f < nf4) r[i] = srec4[f];
    }
#pragma unroll
    for (int i = 0; i < 10; i++) {
        int f = tid + i * THREADS;
        if (f < nf4) {
            int a = f / 20, c = f % 20;
            float* d = &ssc[a][c * 4];
            d[0] = r[i].x; d[1] = r[i].y; d[2] = r[i].z; d[3] = r[i].w;
        }
    }
    __syncthreads();

    const int al = tid & (TILE - 1);
    const int gbase = (tid >> 7) * 16;   // 2 groups x 16 gts
    if (al >= na_tile) return;

    float4 p = spbox[al];
    float w2 = p.z - p.x, h2 = p.w - p.y + eps;
    float a2  = w2 * h2;
    float at2 = atanf(w2 / h2);
    const size_t abs_a = (size_t)abase + al;

#pragma unroll
    for (int k = 0; k < 16; k++) {
        int gi = gbase + k;
        float gx1 = sgx1[gi], gy1 = sgy1[gi], gx2 = sgx2[gi], gy2 = sgy2[gi];
        float iw = fmaxf(fminf(gx2, p.z) - fmaxf(gx1, p.x), 0.0f);
        float ih = fmaxf(fminf(gy2, p.w) - fmaxf(gy1, p.y), 0.0f);
        float inter = iw * ih;
        float uni = sa1[gi] + a2 - inter + eps;
        float iou = inter / uni;
        float cw = fmaxf(gx2, p.z) - fminf(gx1, p.x);
        float ch = fmaxf(gy2, p.w) - fminf(gy1, p.y);
        float c2 = cw * cw + ch * ch + eps;
        float dx = p.x + p.z - gx1 - gx2;
        float dy = p.y + p.w - gy1 - gy2;
        float rho2 = (dx * dx + dy * dy) / 4.0f;
        float dd = at2 - sat1[gi];
        float v = (float)(4.0 / (M_PI * M_PI)) * dd * dd;
        float alpha = v / (v - iou + (1.0f + eps));
        float ov = iou - (rho2 / c2 + v * alpha);
        float sc = ssc[al][slbl[gi]];
        float ov2 = ov * ov;
        met[((size_t)b * NMAX + gi) * NA + abs_a] = sc * (ov2 * ov2 * ov2);
    }
}

// One block per (b, gt) row. Phase A: each wave finds the top-13 of its own
// 2112 elements barrier-free (per-lane top-2 cache + butterfly argmax; rare
// divergent rescan only when a lane wins twice). Phase B: wave 0 merges the
// 4x13 candidates and scatters atomicOr bits. ONE __syncthreads total.
// Tie-break everywhere: (value desc, index asc) — matches lax.top_k.
__global__ __launch_bounds__(THREADS) void topk_kernel(
    const float* __restrict__ met, unsigned int* __restrict__ mask) {
    const int tid  = threadIdx.x;
    const int lane = tid & 63;
    const int w    = tid >> 6;
    const int bid  = blockIdx.x;
    const int b  = bid >> 5;
    const int gi = bid & 31;
    const float* mrow = met + ((size_t)b * NMAX + gi) * NA;

    float m[NPT];
#pragma unroll
    for (int j = 0; j < NPT; j++) {
        int a = j * THREADS + tid;
        m[j] = (a < NA) ? mrow[a] : -INFINITY;
    }

    // per-lane top-2 cache
    float bv0 = -INFINITY, bv1 = -INFINITY;
    int   ba0 = 0x7FFFFFFF, ba1 = 0x7FFFFFFF;
#pragma unroll
    for (int j = 0; j < NPT; j++) {
        float v = m[j]; int a = j * THREADS + tid;
        bool beats0 = (v > bv0) || (v == bv0 && a < ba0);
        bool beats1 = (v > bv1) || (v == bv1 && a < ba1);
        if (beats0) { bv1 = bv0; ba1 = ba0; bv0 = v; ba0 = a; }
        else if (beats1) { bv1 = v; ba1 = a; }
    }
    bool valid1 = true;

    float rv = -INFINITY; int ra = 0x7FFFFFFF;   // lane k holds k-th wave winner
    for (int k = 0; k < TOPK; k++) {
        float v = bv0; int a = ba0;
#pragma unroll
        for (int s = 1; s < 64; s <<= 1) {
            float ov = __shfl_xor(v, s);
            int   oa = __shfl_xor(a, s);
            if (ov > v || (ov == v && oa < a)) { v = ov; a = oa; }
        }
        if (lane == k) { rv = v; ra = a; }
        if (ba0 == a) {            // unique owner (lanes own disjoint indices)
            if (valid1) { bv0 = bv1; ba0 = ba1; valid1 = false; }
            else {                 // rare: lane won >=2 times -> rescan below (v,a)
                float nv = -INFINITY; int na_ = 0x7FFFFFFF;
#pragma unroll
                for (int j = 0; j < NPT; j++) {
                    float mv = m[j]; int ma = j * THREADS + tid;
                    bool below = (mv < v) || (mv == v && ma > a);
                    bool beats = (mv > nv) || (mv == nv && ma < na_);
                    if (below && beats) { nv = mv; na_ = ma; }
                }
                bv0 = nv; ba0 = na_;
            }
        }
    }

    __shared__ float lv[4 * TOPK];
    __shared__ int   la[4 * TOPK];
    if (lane < TOPK) { lv[w * TOPK + lane] = rv; la[w * TOPK + lane] = ra; }
    __syncthreads();

    if (w == 0) {
        float v = (lane < 4 * TOPK) ? lv[lane] : -INFINITY;
        int   a = (lane < 4 * TOPK) ? la[lane] : 0x7FFFFFFF;
        for (int k = 0; k < TOPK; k++) {
            float wv = v; int wa = a;
#pragma unroll
            for (int s = 1; s < 64; s <<= 1) {
                float ov = __shfl_xor(wv, s);
                int   oa = __shfl_xor(wa, s);
                if (ov > wv || (ov == wv && oa < wa)) { wv = ov; wa = oa; }
            }
            if (lane == 0) atomicOr(&mask[(size_t)b * NA + wa], 1u << gi);
            if (a == wa) { v = -INFINITY; a = 0x7FFFFFFF; }  // consume
        }
    }
}

// Fused assign + score writer. Block = 256 anchors; ALL 256 threads resolve one
// anchor each (same arithmetic -> bit-identical), then stream the 256x20 float4
// one-hot score rows with nontemporal lane-consecutive stores (final outputs,
// never re-read -> bypass L2/L3).
__global__ __launch_bounds__(THREADS) void assign_score_kernel(
    const float* __restrict__ pd_bboxes, const int* __restrict__ gt_labels,
    const float* __restrict__ gt_bboxes, const unsigned int* __restrict__ mask,
    float* __restrict__ out) {
    const int tid = threadIdx.x;
    const int ab = blockIdx.x * THREADS;
    const int idx = ab + tid;
    __shared__ float spo[THREADS];
    __shared__ int   slb[THREADS];   // label if fg else -1

    {
        int b = idx / NA;
        unsigned msk = mask[idx];
        int tgt = msk ? (__ffs(msk) - 1) : 0;   // argmax over gt = first set bit
        float4 gb = ((const float4*)gt_bboxes)[b * NMAX + tgt];
        int lbl = gt_labels[b * NMAX + tgt];
        float4 p = ((const float4*)pd_bboxes)[idx];

        float sum = 0.0f;
        int cnt = 0;
        unsigned mm = msk;
        while (mm) {                             // ascending gt order = JAX sum order
            int i = __ffs(mm) - 1;
            mm &= mm - 1;
            float4 g = ((const float4*)gt_bboxes)[b * NMAX + i];
            sum += ciou_f(g.x, g.y, g.z, g.w, p.x, p.y, p.z, p.w);
            cnt++;
        }
        float po = fminf(fmaxf(sum / ((float)cnt + 1e-9f), 0.0f), 1.0f);

        bool fg = (msk != 0);
        __builtin_nontemporal_store(fg ? (float)lbl : 80.0f, &out[idx]);
        f32x4 gbv = { gb.x, gb.y, gb.z, gb.w };
        __builtin_nontemporal_store(gbv, (f32x4*)(out + OFF_BOX) + idx);
        __builtin_nontemporal_store(fg ? 1.0f : 0.0f, &out[OFF_FG + idx]);
        __builtin_nontemporal_store((float)tgt, &out[OFF_TGT + idx]);
        spo[tid] = po;
        slb[tid] = fg ? lbl : -1;
    }
    __syncthreads();

    f32x4* obase = (f32x4*)(out + OFF_SCR + (size_t)ab * NC);
#pragma unroll
    for (int i = 0; i < 20; i++) {
        int f = tid + i * THREADS;       // 0..5119, lane-consecutive
        int a = f / 20, c = f % 20;
        int lbl = slb[a];
        f32x4 z = { 0.f, 0.f, 0.f, 0.f };
        if ((lbl >> 2) == c) z[lbl & 3] = spo[a];
        __builtin_nontemporal_store(z, obase + f);
    }
}

extern "C" void kernel_launch(void* const* d_in, const int* in_sizes, int n_in,
                              void* d_out, int out_size, void* d_ws, size_t ws_size,
                              hipStream_t stream) {
    const float* pd_scores = (const float*)d_in[0];
    const float* pd_bboxes = (const float*)d_in[1];
    // d_in[2] anc_points: unused by reference
    const int*   gt_labels = (const int*)d_in[3];
    const float* gt_bboxes = (const float*)d_in[4];
    // d_in[5] mask_gt: unused by reference (all ones)

    float* out = (float*)d_out;
    unsigned int* mask = (unsigned int*)d_ws;
    float* met = out + OFF_SCR;   // score plane doubles as met scratch

    dim3 g1((NA + TILE - 1) / TILE, BATCH);
    metric_kernel<<<g1, THREADS, 0, stream>>>(pd_scores, pd_bboxes,
                                              gt_labels, gt_bboxes, met, mask);
    topk_kernel<<<BATCH * NMAX, THREADS, 0, stream>>>(met, mask);
    assign_score_kernel<<<BATCH * NA / THREADS, THREADS, 0, stream>>>(
        pd_bboxes, gt_labels, gt_bboxes, mask, out);
}